// Round 1
// baseline (368.210 us; speedup 1.0000x reference)
//
#include <hip/hip_runtime.h>
#include <math.h>

// Problem constants (fixed by setup_inputs)
#define NB    8
#define NN    100
#define NPRED (NB*NN)     // 800
#define MT    20
#define NT    (NB*MT)     // 160
#define HW    25600
#define NCLS  80

// ---------------- row squared-norm (|p|^2, |t|^2) ----------------
__global__ __launch_bounds__(256) void row_sqnorm(const float* __restrict__ X,
                                                  float* __restrict__ out, int ncols){
  int row = blockIdx.x;
  const float* xr = X + (size_t)row * ncols;
  double s = 0.0;
  for (int k = threadIdx.x; k < ncols; k += 256){ float v = xr[k]; s += (double)v * (double)v; }
  __shared__ double red[256];
  red[threadIdx.x] = s; __syncthreads();
  for (int off = 128; off > 0; off >>= 1){
    if (threadIdx.x < off) red[threadIdx.x] += red[threadIdx.x + off];
    __syncthreads();
  }
  if (threadIdx.x == 0) out[row] = (float)red[0];
}

// ---------------- fp32 GEMM partial: part[ks][pred][t] = pm[pred,krange] . tm[t,krange] ----------------
#define BM 80
#define BN 80
#define BK 32
__global__ __launch_bounds__(256) void gemm_part(const float* __restrict__ A,
                                                 const float* __restrict__ Bm,
                                                 float* __restrict__ part, int Kc){
  __shared__ float As[BK][BM + 1];
  __shared__ float Bs[BK][BN + 1];
  const int p0 = blockIdx.x * BM, t0 = blockIdx.y * BN;
  const int k0 = blockIdx.z * Kc;
  float acc[5][5] = {};
  const int tx = threadIdx.x & 15, ty = threadIdx.x >> 4;

  for (int kc = 0; kc < Kc; kc += BK){
    for (int i = threadIdx.x; i < BM * BK; i += 256){
      int p = i >> 5, kk = i & 31;
      As[kk][p] = A[(size_t)(p0 + p) * HW + (k0 + kc + kk)];
    }
    for (int i = threadIdx.x; i < BN * BK; i += 256){
      int t = i >> 5, kk = i & 31;
      Bs[kk][t] = Bm[(size_t)(t0 + t) * HW + (k0 + kc + kk)];
    }
    __syncthreads();
    #pragma unroll 8
    for (int kk = 0; kk < BK; kk++){
      float a[5], b[5];
      #pragma unroll
      for (int q = 0; q < 5; q++) a[q] = As[kk][ty * 5 + q];
      #pragma unroll
      for (int r = 0; r < 5; r++) b[r] = Bs[kk][tx * 5 + r];
      #pragma unroll
      for (int q = 0; q < 5; q++)
        #pragma unroll
        for (int r = 0; r < 5; r++) acc[q][r] += a[q] * b[r];
    }
    __syncthreads();
  }
  float* dst = part + (size_t)blockIdx.z * (NPRED * NT);
  #pragma unroll
  for (int q = 0; q < 5; q++)
    #pragma unroll
    for (int r = 0; r < 5; r++)
      dst[(size_t)(p0 + ty * 5 + q) * NT + (t0 + tx * 5 + r)] = acc[q][r];
}

// ---------------- finalize: reduce K-splits, dice + focal class cost ----------------
__global__ __launch_bounds__(256) void finalize(const float* __restrict__ part, int KS,
                                                const float* __restrict__ pnorm,
                                                const float* __restrict__ tnorm,
                                                const float* __restrict__ logits,
                                                const int* __restrict__ tgt_ids,
                                                float* __restrict__ C){
  int idx = blockIdx.x * 256 + threadIdx.x;
  if (idx >= NPRED * NT) return;
  int pred = idx / NT, t = idx - pred * NT;
  double dot = 0.0;
  for (int ks = 0; ks < KS; ks++) dot += (double)part[(size_t)ks * (NPRED * NT) + idx];
  double num = 2.0 * dot;
  double den = (double)pnorm[pred] + (double)tnorm[t];
  double mask_score = -((num + 1e-4) / (den + 1e-4));
  int cls = tgt_ids[t];
  double x  = (double)logits[pred * NCLS + cls];
  double pl = 1.0 / (1.0 + exp(-x));
  double pos = 0.25 * (1.0 - pl) * (1.0 - pl) * (-log(pl + 1e-8));
  double neg = 0.75 * pl * pl * (-log(1.0 - pl + 1e-8));
  double cv = mask_score * 2.0 + (pos - neg);
  float o = (float)cv;
  if (!isfinite(o)) o = 0.0f;
  C[idx] = o;
}

// ---------------- Hungarian (JV), exact fp64 replica of reference _lsa ----------------
// Per image: cost (n=20 targets) x (m=100 preds) = C[img,:,img*20:(i+1)*20] transposed.
__global__ __launch_bounds__(64) void hungarian(const float* __restrict__ C,
                                                float* __restrict__ rows_out,
                                                float* __restrict__ cols_out){
  const int img = blockIdx.x;
  const int lane = threadIdx.x;                   // 0..63
  __shared__ double cost[MT][NN];
  __shared__ double u[MT + 1], v[NN + 1], minv[NN + 1];
  __shared__ int pcol[NN + 1], way[NN + 1], used[NN + 1];
  __shared__ int shI0;

  for (int i = lane; i < MT * NN; i += 64){
    int t = i / NN, p = i - t * NN;
    cost[t][p] = (double)C[(size_t)img * NN * NT + (size_t)p * NT + img * MT + t];
  }
  for (int j = lane; j <= NN; j += 64){ v[j] = 0.0; pcol[j] = 0; way[j] = 0; }
  for (int j = lane; j <= MT; j += 64) u[j] = 0.0;
  __syncthreads();

  const double INF = 1e18;
  const int jA = lane + 1;       // 1..64 (always valid, m=100)
  const int jB = lane + 65;      // 65..128 (valid if <=100)

  for (int i = 1; i <= MT; i++){
    if (lane == 0) pcol[0] = i;
    for (int j = lane; j <= NN; j += 64){ minv[j] = INF; used[j] = 0; }
    __syncthreads();
    int j0 = 0;
    while (true){
      if (lane == 0){ used[j0] = 1; shI0 = pcol[j0]; }
      __syncthreads();
      const int i0 = shI0;
      const double ui0 = u[i0];
      // relax free columns (same elementwise fp64 ops as reference)
      if (!used[jA]){
        double cur = cost[i0 - 1][jA - 1] - ui0 - v[jA];
        if (cur < minv[jA]){ minv[jA] = cur; way[jA] = j0; }
      }
      if (jB <= NN && !used[jB]){
        double cur = cost[i0 - 1][jB - 1] - ui0 - v[jB];
        if (cur < minv[jB]){ minv[jB] = cur; way[jB] = j0; }
      }
      __syncthreads();
      // argmin over masked minv, np.argmin tie-break (smallest index)
      double bv = used[jA] ? INF : minv[jA];
      int bi = jA;
      if (jB <= NN){
        double v2 = used[jB] ? INF : minv[jB];
        if (v2 < bv){ bv = v2; bi = jB; }
      }
      #pragma unroll
      for (int off = 32; off >= 1; off >>= 1){
        double ov = __shfl_xor(bv, off);
        int    oi = __shfl_xor(bi, off);
        if (ov < bv || (ov == bv && oi < bi)){ bv = ov; bi = oi; }
      }
      const double delta = bv;
      const int j1 = bi;
      // dual updates: used cols (incl. j=0) get u/v shift, free cols minv -= delta
      if (lane == 0){ u[pcol[0]] += delta; v[0] -= delta; }
      if (used[jA]){ u[pcol[jA]] += delta; v[jA] -= delta; } else { minv[jA] -= delta; }
      if (jB <= NN){
        if (used[jB]){ u[pcol[jB]] += delta; v[jB] -= delta; } else { minv[jB] -= delta; }
      }
      __syncthreads();
      j0 = j1;
      if (pcol[j0] == 0) break;
    }
    // augmenting path flip (serial, lane 0)
    if (lane == 0){
      int jj = j0;
      while (true){ int jp = way[jj]; pcol[jj] = pcol[jp]; jj = jp; if (jj == 0) break; }
    }
    __syncthreads();
  }
  // emit pairs sorted by pred index (ascending j == reference's argsort(rows))
  if (lane == 0){
    int k = 0;
    for (int j = 1; j <= NN; j++){
      if (pcol[j] != 0){
        rows_out[img * MT + k] = (float)(j - 1);
        cols_out[img * MT + k] = (float)(pcol[j] - 1);
        k++;
      }
    }
  }
}

extern "C" void kernel_launch(void* const* d_in, const int* in_sizes, int n_in,
                              void* d_out, int out_size, void* d_ws, size_t ws_size,
                              hipStream_t stream) {
  const float* pm     = (const float*)d_in[0];   // (8,100,160,160)
  const float* logits = (const float*)d_in[1];   // (8,100,80)
  const float* tm     = (const float*)d_in[2];   // (160,160,160)
  const int*   tids   = (const int*)d_in[3];     // (160,)

  float* C        = (float*)d_out;               // 128000
  float* rows_out = C + NPRED * NT;              // +160
  float* cols_out = rows_out + NB * MT;          // +160

  char* ws = (char*)d_ws;
  float* pnorm = (float*)ws;                     // 800 floats
  float* tnorm = (float*)(ws + 4096);            // 160 floats
  float* part  = (float*)(ws + 8192);            // KS * 128000 floats

  int KS = 32;
  while (KS > 1 && (size_t)8192 + (size_t)KS * NPRED * NT * 4 > ws_size) KS >>= 1;
  int Kc = HW / KS;

  row_sqnorm<<<NPRED, 256, 0, stream>>>(pm, pnorm, HW);
  row_sqnorm<<<NT,    256, 0, stream>>>(tm, tnorm, HW);
  dim3 g(NPRED / BM, NT / BN, KS);
  gemm_part<<<g, 256, 0, stream>>>(pm, tm, part, Kc);
  finalize<<<(NPRED * NT + 255) / 256, 256, 0, stream>>>(part, KS, pnorm, tnorm, logits, tids, C);
  hungarian<<<NB, 64, 0, stream>>>(C, rows_out, cols_out);
}

// Round 2
// 137.524 us; speedup vs baseline: 2.6774x; 2.6774x over previous
//
#include <hip/hip_runtime.h>
#include <math.h>

#define NB    8
#define NN    100
#define NPRED (NB*NN)     // 800
#define MT    20
#define NT    (NB*MT)     // 160
#define HW    25600
#define NCLS  80

typedef float  f32x4  __attribute__((ext_vector_type(4)));
typedef short  short8 __attribute__((ext_vector_type(8)));
typedef unsigned short u16x8 __attribute__((ext_vector_type(8)));

static __device__ __forceinline__ unsigned short f2bf(float f){
  unsigned u = __float_as_uint(f);
  unsigned r = (u + 0x7fffu + ((u >> 16) & 1u)) >> 16;
  return (unsigned short)r;
}
static __device__ __forceinline__ float bf2f(unsigned short h){
  return __uint_as_float(((unsigned)h) << 16);
}

// ---------------- split-bf16 MFMA GEMM with K-split and fused row norms ----------------
// Block tile: BM=96 (rows of pm) x BN=160 (ALL targets) x BK=64.
// 4 waves in 2x2 grid, wave tile 48x80 (3x5 frags of 16x16x32 MFMA).
// Each fp32 element split hi/lo bf16; product = hi*hi + hi*lo + lo*hi (err ~2^-18).
__global__ __launch_bounds__(256, 2)
void gemm_split(const float* __restrict__ A, const float* __restrict__ Bm,
                float* __restrict__ part, float* __restrict__ pnp,
                float* __restrict__ tnp, int Kc, int ksteps){
  __shared__ unsigned short sAhi[96*64], sAlo[96*64];
  __shared__ unsigned short sBhi[160*64], sBlo[160*64];

  const int t     = threadIdx.x;
  const int mtile = blockIdx.x, ks = blockIdx.y;
  const int lane  = t & 63, w = t >> 6;
  const int wr = w >> 1, wc = w & 1;
  const int fr = lane & 15, fq = lane >> 4;
  const int r0 = t >> 3, ksl = t & 7;     // staging: row group, k-slot
  const int kbase = ks * Kc;

  f32x4 acc[3][5];
  #pragma unroll
  for (int r = 0; r < 3; r++)
    #pragma unroll
    for (int c = 0; c < 5; c++) acc[r][c] = (f32x4){0.f, 0.f, 0.f, 0.f};

  float asum[3] = {0.f, 0.f, 0.f};
  float tsum[5] = {0.f, 0.f, 0.f, 0.f, 0.f};

  for (int step = 0; step < ksteps; ++step){
    const int k0 = kbase + step * 64;
    // ---- stage A (96x64): 3 slots of 8 k per thread ----
    #pragma unroll
    for (int j = 0; j < 3; ++j){
      const int rl   = r0 + 32 * j;
      const int grow = mtile * 96 + rl;
      float v[8];
      if (grow < NPRED){
        const float4* p = (const float4*)(A + (size_t)grow * HW + k0 + ksl * 8);
        float4 x0 = p[0], x1 = p[1];
        v[0]=x0.x; v[1]=x0.y; v[2]=x0.z; v[3]=x0.w;
        v[4]=x1.x; v[5]=x1.y; v[6]=x1.z; v[7]=x1.w;
      } else {
        #pragma unroll
        for (int i = 0; i < 8; i++) v[i] = 0.f;
      }
      u16x8 H, L;
      #pragma unroll
      for (int i = 0; i < 8; i++){
        asum[j] += v[i] * v[i];
        unsigned short h = f2bf(v[i]);
        H[i] = h;
        L[i] = f2bf(v[i] - bf2f(h));
      }
      const int eo = rl * 64 + ((ksl ^ (rl & 7)) << 3);
      *(u16x8*)&sAhi[eo] = H;
      *(u16x8*)&sAlo[eo] = L;
    }
    // ---- stage B (160x64): 5 slots per thread ----
    #pragma unroll
    for (int j = 0; j < 5; ++j){
      const int rl = r0 + 32 * j;
      const float4* p = (const float4*)(Bm + (size_t)rl * HW + k0 + ksl * 8);
      float4 x0 = p[0], x1 = p[1];
      float v[8];
      v[0]=x0.x; v[1]=x0.y; v[2]=x0.z; v[3]=x0.w;
      v[4]=x1.x; v[5]=x1.y; v[6]=x1.z; v[7]=x1.w;
      u16x8 H, L;
      #pragma unroll
      for (int i = 0; i < 8; i++){
        tsum[j] += v[i] * v[i];
        unsigned short h = f2bf(v[i]);
        H[i] = h;
        L[i] = f2bf(v[i] - bf2f(h));
      }
      const int eo = rl * 64 + ((ksl ^ (rl & 7)) << 3);
      *(u16x8*)&sBhi[eo] = H;
      *(u16x8*)&sBlo[eo] = L;
    }
    __syncthreads();
    // ---- MFMA: 2 kk halves x (3x5 frags) x 3 precision terms ----
    #pragma unroll
    for (int kk = 0; kk < 2; ++kk){
      const int slot = kk * 4 + fq;
      const int swz  = (slot ^ (fr & 7)) << 3;
      short8 ah[3], al[3], bh[5], bl[5];
      #pragma unroll
      for (int r = 0; r < 3; r++){
        const int eo = (wr * 48 + r * 16 + fr) * 64 + swz;
        ah[r] = *(const short8*)&sAhi[eo];
        al[r] = *(const short8*)&sAlo[eo];
      }
      #pragma unroll
      for (int c = 0; c < 5; c++){
        const int eo = (wc * 80 + c * 16 + fr) * 64 + swz;
        bh[c] = *(const short8*)&sBhi[eo];
        bl[c] = *(const short8*)&sBlo[eo];
      }
      #pragma unroll
      for (int r = 0; r < 3; r++)
        #pragma unroll
        for (int c = 0; c < 5; c++){
          acc[r][c] = __builtin_amdgcn_mfma_f32_16x16x32_bf16(ah[r], bh[c], acc[r][c], 0, 0, 0);
          acc[r][c] = __builtin_amdgcn_mfma_f32_16x16x32_bf16(ah[r], bl[c], acc[r][c], 0, 0, 0);
          acc[r][c] = __builtin_amdgcn_mfma_f32_16x16x32_bf16(al[r], bh[c], acc[r][c], 0, 0, 0);
        }
    }
    __syncthreads();
  }

  // ---- fused norms: 8-lane reduce, one partial per row per k-split ----
  #pragma unroll
  for (int j = 0; j < 3; ++j){
    float s = asum[j];
    s += __shfl_xor(s, 1); s += __shfl_xor(s, 2); s += __shfl_xor(s, 4);
    if ((t & 7) == 0){
      const int grow = mtile * 96 + r0 + 32 * j;
      if (grow < NPRED) pnp[(size_t)ks * NPRED + grow] = s;
    }
  }
  if (mtile == 0){
    #pragma unroll
    for (int j = 0; j < 5; ++j){
      float s = tsum[j];
      s += __shfl_xor(s, 1); s += __shfl_xor(s, 2); s += __shfl_xor(s, 4);
      if ((t & 7) == 0) tnp[(size_t)ks * NT + r0 + 32 * j] = s;
    }
  }

  // ---- store partial products ----
  float* dst = part + (size_t)ks * (NPRED * NT);
  #pragma unroll
  for (int r = 0; r < 3; r++)
    #pragma unroll
    for (int c = 0; c < 5; c++)
      #pragma unroll
      for (int i = 0; i < 4; i++){
        const int grow = mtile * 96 + wr * 48 + r * 16 + fq * 4 + i;
        if (grow < NPRED)
          dst[(size_t)grow * NT + wc * 80 + c * 16 + fr] = acc[r][c][i];
      }
}

// ---------------- reduce norm partials over K-splits ----------------
__global__ __launch_bounds__(256) void norm_reduce(const float* __restrict__ pnp,
                                                   const float* __restrict__ tnp,
                                                   float* __restrict__ pn,
                                                   float* __restrict__ tn, int KS){
  int idx = blockIdx.x * 256 + threadIdx.x;
  if (idx < NPRED){
    float s = 0.f;
    for (int ks = 0; ks < KS; ks++) s += pnp[(size_t)ks * NPRED + idx];
    pn[idx] = s;
  } else if (idx < NPRED + NT){
    int j = idx - NPRED;
    float s = 0.f;
    for (int ks = 0; ks < KS; ks++) s += tnp[(size_t)ks * NT + j];
    tn[j] = s;
  }
}

// ---------------- finalize: reduce K-splits, dice + focal class cost ----------------
__global__ __launch_bounds__(256) void finalize(const float* __restrict__ part, int KS,
                                                const float* __restrict__ pnorm,
                                                const float* __restrict__ tnorm,
                                                const float* __restrict__ logits,
                                                const int* __restrict__ tgt_ids,
                                                float* __restrict__ C){
  int idx = blockIdx.x * 256 + threadIdx.x;
  if (idx >= NPRED * NT) return;
  int pred = idx / NT, t = idx - pred * NT;
  double dot = 0.0;
  for (int ks = 0; ks < KS; ks++) dot += (double)part[(size_t)ks * (NPRED * NT) + idx];
  double num = 2.0 * dot;
  double den = (double)pnorm[pred] + (double)tnorm[t];
  double mask_score = -((num + 1e-4) / (den + 1e-4));
  int cls = tgt_ids[t];
  double x  = (double)logits[pred * NCLS + cls];
  double pl = 1.0 / (1.0 + exp(-x));
  double pos = 0.25 * (1.0 - pl) * (1.0 - pl) * (-log(pl + 1e-8));
  double neg = 0.75 * pl * pl * (-log(1.0 - pl + 1e-8));
  double cv = mask_score * 2.0 + (pos - neg);
  float o = (float)cv;
  if (!isfinite(o)) o = 0.0f;
  C[idx] = o;
}

// ---------------- Hungarian (JV), exact fp64 replica of reference _lsa ----------------
__global__ __launch_bounds__(64) void hungarian(const float* __restrict__ C,
                                                float* __restrict__ rows_out,
                                                float* __restrict__ cols_out){
  const int img = blockIdx.x;
  const int lane = threadIdx.x;                   // 0..63
  __shared__ double cost[MT][NN];
  __shared__ double u[MT + 1], v[NN + 1], minv[NN + 1];
  __shared__ int pcol[NN + 1], way[NN + 1], used[NN + 1];
  __shared__ int shI0;

  for (int i = lane; i < MT * NN; i += 64){
    int t = i / NN, p = i - t * NN;
    cost[t][p] = (double)C[(size_t)img * NN * NT + (size_t)p * NT + img * MT + t];
  }
  for (int j = lane; j <= NN; j += 64){ v[j] = 0.0; pcol[j] = 0; way[j] = 0; }
  for (int j = lane; j <= MT; j += 64) u[j] = 0.0;
  __syncthreads();

  const double INF = 1e18;
  const int jA = lane + 1;
  const int jB = lane + 65;

  for (int i = 1; i <= MT; i++){
    if (lane == 0) pcol[0] = i;
    for (int j = lane; j <= NN; j += 64){ minv[j] = INF; used[j] = 0; }
    __syncthreads();
    int j0 = 0;
    while (true){
      if (lane == 0){ used[j0] = 1; shI0 = pcol[j0]; }
      __syncthreads();
      const int i0 = shI0;
      const double ui0 = u[i0];
      if (!used[jA]){
        double cur = cost[i0 - 1][jA - 1] - ui0 - v[jA];
        if (cur < minv[jA]){ minv[jA] = cur; way[jA] = j0; }
      }
      if (jB <= NN && !used[jB]){
        double cur = cost[i0 - 1][jB - 1] - ui0 - v[jB];
        if (cur < minv[jB]){ minv[jB] = cur; way[jB] = j0; }
      }
      __syncthreads();
      double bv = used[jA] ? INF : minv[jA];
      int bi = jA;
      if (jB <= NN){
        double v2 = used[jB] ? INF : minv[jB];
        if (v2 < bv){ bv = v2; bi = jB; }
      }
      #pragma unroll
      for (int off = 32; off >= 1; off >>= 1){
        double ov = __shfl_xor(bv, off);
        int    oi = __shfl_xor(bi, off);
        if (ov < bv || (ov == bv && oi < bi)){ bv = ov; bi = oi; }
      }
      const double delta = bv;
      const int j1 = bi;
      if (lane == 0){ u[pcol[0]] += delta; v[0] -= delta; }
      if (used[jA]){ u[pcol[jA]] += delta; v[jA] -= delta; } else { minv[jA] -= delta; }
      if (jB <= NN){
        if (used[jB]){ u[pcol[jB]] += delta; v[jB] -= delta; } else { minv[jB] -= delta; }
      }
      __syncthreads();
      j0 = j1;
      if (pcol[j0] == 0) break;
    }
    if (lane == 0){
      int jj = j0;
      while (true){ int jp = way[jj]; pcol[jj] = pcol[jp]; jj = jp; if (jj == 0) break; }
    }
    __syncthreads();
  }
  if (lane == 0){
    int k = 0;
    for (int j = 1; j <= NN; j++){
      if (pcol[j] != 0){
        rows_out[img * MT + k] = (float)(j - 1);
        cols_out[img * MT + k] = (float)(pcol[j] - 1);
        k++;
      }
    }
  }
}

extern "C" void kernel_launch(void* const* d_in, const int* in_sizes, int n_in,
                              void* d_out, int out_size, void* d_ws, size_t ws_size,
                              hipStream_t stream) {
  const float* pm     = (const float*)d_in[0];   // (8,100,160,160)
  const float* logits = (const float*)d_in[1];   // (8,100,80)
  const float* tm     = (const float*)d_in[2];   // (160,160,160)
  const int*   tids   = (const int*)d_in[3];     // (160,)

  float* C        = (float*)d_out;               // 128000
  float* rows_out = C + NPRED * NT;
  float* cols_out = rows_out + NB * MT;

  // pick largest K-split that fits in workspace
  static const int ks_opts[] = {50, 25, 10, 5, 2, 1};   // Kc = 512..25600, all %64==0
  int KS = 1; size_t part_off = 0;
  for (int oi = 0; oi < 6; oi++){
    int o = ks_opts[oi];
    size_t norms = (size_t)o * NPRED * 4 + (size_t)o * NT * 4 + NPRED * 4 + NT * 4;
    size_t po = (norms + 255) & ~(size_t)255;
    size_t need = po + (size_t)o * (NPRED * NT) * 4;
    if (need <= ws_size){ KS = o; part_off = po; break; }
  }
  char* ws = (char*)d_ws;
  float* pnp   = (float*)ws;                                    // [KS][800]
  float* tnp   = (float*)(ws + (size_t)KS * NPRED * 4);         // [KS][160]
  float* pnorm = (float*)(ws + (size_t)KS * (NPRED + NT) * 4);  // [800]
  float* tnorm = pnorm + NPRED;                                 // [160]
  float* part  = (float*)(ws + part_off);                       // [KS][800*160]

  const int Kc = HW / KS;
  const int ksteps = Kc / 64;

  gemm_split<<<dim3(9, KS), 256, 0, stream>>>(pm, tm, part, pnp, tnp, Kc, ksteps);
  norm_reduce<<<4, 256, 0, stream>>>(pnp, tnp, pnorm, tnorm, KS);
  finalize<<<(NPRED * NT + 255) / 256, 256, 0, stream>>>(part, KS, pnorm, tnorm, logits, tids, C);
  hungarian<<<NB, 64, 0, stream>>>(C, rows_out, cols_out);
}